// Round 6
// baseline (757.480 us; speedup 1.0000x reference)
//
#include <hip/hip_runtime.h>
#include <hip/hip_bf16.h>

// GCNConv via coarse binning (64 targets/bucket) + per-bucket LDS aggregation.
// agg[c] = dinv[c] * ( xs[c] + sum_{e: col[e]==c} xs[row[e]] ),
//   xs[i] = (x@W)[i] * dinv[i],  dinv[i] = rsqrt(1 + indeg(i))
// out = dropout(tanh(agg + b)), JAX partitionable-threefry, key (0,42), p_keep=0.9:
//   bits[i] = o0^o1 of threefry((0,42), 0, i); u = bitcast(bits>>9|0x3f800000)-1; keep = u<0.9.
//
// ws (~19.6 MB): dinv f32[NN] | xsh bf16[NN*64] | packed u32[NE]
//                | bhist i32[NBUCK] | bstart i32[NBUCK+1] | bcur i32[NBUCK]
// packed edge: src (17b) | tgt_local (6b) << 17, bucket = tgt >> 6.

#define NN 100000
#define NE 1600000
#define NBUCK 1563          // ceil(NN/64)
#define P1B 128
#define CHUNK 12500         // P1B * CHUNK == NE exactly

// ---------------- Threefry2x32 (JAX-exact) ----------------
__device__ __forceinline__ unsigned rotl32(unsigned x, int r) {
    return (x << r) | (x >> (32 - r));
}

__device__ __forceinline__ void threefry2x32(unsigned k0, unsigned k1,
                                             unsigned x0, unsigned x1,
                                             unsigned& o0, unsigned& o1) {
    const unsigned ks0 = k0, ks1 = k1, ks2 = k0 ^ k1 ^ 0x1BD11BDAu;
    x0 += ks0; x1 += ks1;
    x0 += x1; x1 = rotl32(x1, 13); x1 ^= x0;
    x0 += x1; x1 = rotl32(x1, 15); x1 ^= x0;
    x0 += x1; x1 = rotl32(x1, 26); x1 ^= x0;
    x0 += x1; x1 = rotl32(x1, 6);  x1 ^= x0;
    x0 += ks1; x1 += ks2 + 1u;
    x0 += x1; x1 = rotl32(x1, 17); x1 ^= x0;
    x0 += x1; x1 = rotl32(x1, 29); x1 ^= x0;
    x0 += x1; x1 = rotl32(x1, 16); x1 ^= x0;
    x0 += x1; x1 = rotl32(x1, 24); x1 ^= x0;
    x0 += ks2; x1 += ks0 + 2u;
    x0 += x1; x1 = rotl32(x1, 13); x1 ^= x0;
    x0 += x1; x1 = rotl32(x1, 15); x1 ^= x0;
    x0 += x1; x1 = rotl32(x1, 26); x1 ^= x0;
    x0 += x1; x1 = rotl32(x1, 6);  x1 ^= x0;
    x0 += ks0; x1 += ks1 + 3u;
    x0 += x1; x1 = rotl32(x1, 17); x1 ^= x0;
    x0 += x1; x1 = rotl32(x1, 29); x1 ^= x0;
    x0 += x1; x1 = rotl32(x1, 16); x1 ^= x0;
    x0 += x1; x1 = rotl32(x1, 24); x1 ^= x0;
    x0 += ks1; x1 += ks2 + 4u;
    x0 += x1; x1 = rotl32(x1, 13); x1 ^= x0;
    x0 += x1; x1 = rotl32(x1, 15); x1 ^= x0;
    x0 += x1; x1 = rotl32(x1, 26); x1 ^= x0;
    x0 += x1; x1 = rotl32(x1, 6);  x1 ^= x0;
    x0 += ks2; x1 += ks0 + 5u;
    o0 = x0; o1 = x1;
}

// ---------------- Kernels ----------------
// Per-block LDS histogram of coarse buckets, flushed with one global atomic per bucket.
__global__ __launch_bounds__(256) void k_bhist(const int* __restrict__ ei,
                                               int* __restrict__ bhist) {
    __shared__ int h[NBUCK];
    const int tid = threadIdx.x;
    for (int i = tid; i < NBUCK; i += 256) h[i] = 0;
    __syncthreads();
    const int base = blockIdx.x * CHUNK;
    for (int i = tid; i < CHUNK; i += 256) {
        const unsigned t = (unsigned)ei[NE + base + i];
        if (t < NN) atomicAdd(&h[t >> 6], 1);
    }
    __syncthreads();
    for (int i = tid; i < NBUCK; i += 256) {
        const int v = h[i];
        if (v) atomicAdd(&bhist[i], v);
    }
}

// Exclusive scan of bhist (1563 <= 2048) in one block; writes bstart and bcur.
__global__ __launch_bounds__(1024) void k_bscan(const int* __restrict__ bhist,
                                                int* __restrict__ bstart,
                                                int* __restrict__ bcur) {
    __shared__ int s[2048];
    const int t = threadIdx.x;
    const int i0 = t, i1 = t + 1024;
    const int c0 = (i0 < NBUCK) ? bhist[i0] : 0;
    const int c1 = (i1 < NBUCK) ? bhist[i1] : 0;
    s[i0] = c0; s[i1] = c1;
    __syncthreads();
    for (int d = 1; d < 2048; d <<= 1) {
        const int a0 = (i0 >= d) ? s[i0 - d] : 0;
        const int a1 = (i1 >= d) ? s[i1 - d] : 0;
        __syncthreads();
        s[i0] += a0; s[i1] += a1;
        __syncthreads();
    }
    if (i0 < NBUCK) { const int b = s[i0] - c0; bstart[i0] = b; bcur[i0] = b; }
    if (i1 < NBUCK) { const int b = s[i1] - c1; bstart[i1] = b; bcur[i1] = b; }
    if (t == 0) bstart[NBUCK] = NE;
}

// Bin edges: LDS hist -> one cursor atomic per (block,bucket) -> grouped writes.
__global__ __launch_bounds__(256) void k_p1(const int* __restrict__ ei,
                                            int* __restrict__ bcur,
                                            unsigned* __restrict__ packed) {
    __shared__ int hb[NBUCK];   // histogram, then block-local base
    __shared__ int lc[NBUCK];   // local cursor
    const int tid = threadIdx.x;
    for (int i = tid; i < NBUCK; i += 256) { hb[i] = 0; lc[i] = 0; }
    __syncthreads();
    const int base = blockIdx.x * CHUNK;
    for (int i = tid; i < CHUNK; i += 256) {
        const unsigned t = (unsigned)ei[NE + base + i];
        if (t < NN) atomicAdd(&hb[t >> 6], 1);
    }
    __syncthreads();
    for (int i = tid; i < NBUCK; i += 256) {
        const int h = hb[i];
        hb[i] = h ? atomicAdd(&bcur[i], h) : 0;
    }
    __syncthreads();
    for (int i = tid; i < CHUNK; i += 256) {
        const unsigned t = (unsigned)ei[NE + base + i];
        if (t >= NN) continue;
        const unsigned src = (unsigned)ei[base + i];
        const int bk = t >> 6;
        const unsigned pos = (unsigned)(hb[bk] + atomicAdd(&lc[bk], 1));
        if (pos < NE) packed[pos] = src | ((t & 63u) << 17);
    }
}

// Per-bucket degree -> dinv (LDS int counts, coalesced packed reads).
__global__ __launch_bounds__(256) void k_p2a(const unsigned* __restrict__ packed,
                                             const int* __restrict__ bstart,
                                             float* __restrict__ dinv) {
    __shared__ int cnt[64];
    const int tid = threadIdx.x;
    const int b = blockIdx.x;
    if (tid < 64) cnt[tid] = 0;
    __syncthreads();
    int s = bstart[b], e = bstart[b + 1];
    if (s < 0) s = 0;
    if (e > NE) e = NE;
    for (int i = s + tid; i < e; i += 256) atomicAdd(&cnt[packed[i] >> 17], 1);
    __syncthreads();
    if (tid < 64) {
        const int c = b * 64 + tid;
        if (c < NN) dinv[c] = rsqrtf(1.0f + (float)cnt[tid]);
    }
}

// x@W (W staged in LDS), scale by dinv, write xsh (bf16).
__global__ __launch_bounds__(256) void k_xw(const float* __restrict__ x,
                                            const float* __restrict__ W,
                                            const float* __restrict__ dinv,
                                            __hip_bfloat16* __restrict__ xsh) {
    __shared__ float Wl[64 * 64];
    __shared__ float xr[4][64];
    const int tid = threadIdx.x;
    for (int i = tid; i < 64 * 64; i += 256) Wl[i] = W[i];
    const int warp = tid >> 6, lane = tid & 63;
    const int row = blockIdx.x * 4 + warp;  // grid exact: 25000*4 == NN
    xr[warp][lane] = x[(size_t)row * 64 + lane];
    __syncthreads();
    float sum = 0.0f;
#pragma unroll
    for (int k = 0; k < 64; ++k) sum = fmaf(xr[warp][k], Wl[k * 64 + lane], sum);
    xsh[(size_t)row * 64 + lane] = __float2bfloat16(sum * dinv[row]);
}

// Per-bucket aggregation in LDS (init = self term), then bias+tanh+dropout.
__global__ __launch_bounds__(256) void k_p2b(const unsigned* __restrict__ packed,
                                             const int* __restrict__ bstart,
                                             const __hip_bfloat16* __restrict__ xsh,
                                             const float* __restrict__ dinv,
                                             const float* __restrict__ bias,
                                             float* __restrict__ out) {
    __shared__ float acc[64 * 64];  // [tgt_local][dim], 16 KB
    const int tid = threadIdx.x;
    const int b = blockIdx.x;
    const long long pbase = (long long)b * 4096;
    // init with self-loop terms (coalesced: acc[idx] <- xsh[b*4096+idx])
    for (int idx = tid; idx < 4096; idx += 256) {
        const long long p = pbase + idx;
        acc[idx] = (p < (long long)NN * 64) ? __bfloat162float(xsh[p]) : 0.0f;
    }
    __syncthreads();
    int s = bstart[b], e = bstart[b + 1];
    if (s < 0) s = 0;
    if (e > NE) e = NE;
    const int wid = tid >> 6, lane = tid & 63;
    for (int i = s + wid; i < e; i += 4) {
        const unsigned pk = packed[i];
        const int src = (int)(pk & 0x1FFFFu);
        const int tl = (int)(pk >> 17);
        const float v = __bfloat162float(xsh[(size_t)src * 64 + lane]);
        atomicAdd(&acc[(tl << 6) + lane], v);  // ds_add_f32
    }
    __syncthreads();
    // finalize: bias + tanh + JAX dropout, coalesced out writes
    for (int idx = tid; idx < 4096; idx += 256) {
        const long long p = pbase + idx;
        if (p >= (long long)NN * 64) break;
        const int c = (int)(p >> 6);
        unsigned o0, o1;
        threefry2x32(0u, 42u, 0u, (unsigned)p, o0, o1);
        const unsigned bits = o0 ^ o1;
        const float u = __uint_as_float((bits >> 9) | 0x3f800000u) - 1.0f;
        const float h = tanhf(dinv[c] * acc[idx] + bias[idx & 63]);
        out[p] = (u < 0.9f) ? h / 0.9f : 0.0f;
    }
}

extern "C" void kernel_launch(void* const* d_in, const int* in_sizes, int n_in,
                              void* d_out, int out_size, void* d_ws, size_t ws_size,
                              hipStream_t stream) {
    const float* x  = (const float*)d_in[0];
    const float* W  = (const float*)d_in[1];
    const float* b  = (const float*)d_in[2];
    const int*   ei = (const int*)d_in[3];
    float* out = (float*)d_out;

    float* dinv = (float*)d_ws;                          // f32[NN]
    __hip_bfloat16* xsh = (__hip_bfloat16*)(dinv + NN);  // bf16[NN*64]
    unsigned* packed = (unsigned*)(xsh + (size_t)NN * 64);  // u32[NE]
    int* bhist  = (int*)(packed + NE);                   // i32[NBUCK]
    int* bstart = bhist + NBUCK;                         // i32[NBUCK+1]
    int* bcur   = bstart + NBUCK + 1;                    // i32[NBUCK]

    hipMemsetAsync(bhist, 0, NBUCK * sizeof(int), stream);
    k_bhist<<<P1B, 256, 0, stream>>>(ei, bhist);
    k_bscan<<<1, 1024, 0, stream>>>(bhist, bstart, bcur);
    k_p1<<<P1B, 256, 0, stream>>>(ei, bcur, packed);
    k_p2a<<<NBUCK, 256, 0, stream>>>(packed, bstart, dinv);
    k_xw<<<NN / 4, 256, 0, stream>>>(x, W, dinv, xsh);
    k_p2b<<<NBUCK, 256, 0, stream>>>(packed, bstart, xsh, dinv, b, out);
}

// Round 7
// 752.666 us; speedup vs baseline: 1.0064x; 1.0064x over previous
//
#include <hip/hip_runtime.h>
#include <hip/hip_bf16.h>

// GCNConv via coarse binning (64 targets/bucket) + per-bucket LDS aggregation.
// agg[c] = dinv[c] * ( xs[c] + sum_{e: col[e]==c} xs[row[e]] ),
//   xs[i] = (x@W)[i] * dinv[i],  dinv[i] = rsqrt(1 + indeg(i))
// out = dropout(tanh(agg + b)), JAX partitionable-threefry, key (0,42), p_keep=0.9:
//   bits[i] = o0^o1 of threefry((0,42), 0, i); u = bitcast(bits>>9|0x3f800000)-1; keep = u<0.9.
//
// ws (~19.6 MB): dinv f32[NN] | xsh bf16[NN*64] | packed u32[NE]
//                | bhist i32[NBUCK] | bstart i32[NBUCK+1] | bcur i32[NBUCK]
// packed edge: src (17b) | tgt_local (6b) << 17, bucket = tgt >> 6.

#define NN 100000
#define NE 1600000
#define NBUCK 1563          // ceil(NN/64)
#define P1B 128
#define CHUNK 12500         // P1B * CHUNK == NE exactly

// ---------------- Threefry2x32 (JAX-exact) ----------------
__device__ __forceinline__ unsigned rotl32(unsigned x, int r) {
    return (x << r) | (x >> (32 - r));
}

__device__ __forceinline__ void threefry2x32(unsigned k0, unsigned k1,
                                             unsigned x0, unsigned x1,
                                             unsigned& o0, unsigned& o1) {
    const unsigned ks0 = k0, ks1 = k1, ks2 = k0 ^ k1 ^ 0x1BD11BDAu;
    x0 += ks0; x1 += ks1;
    x0 += x1; x1 = rotl32(x1, 13); x1 ^= x0;
    x0 += x1; x1 = rotl32(x1, 15); x1 ^= x0;
    x0 += x1; x1 = rotl32(x1, 26); x1 ^= x0;
    x0 += x1; x1 = rotl32(x1, 6);  x1 ^= x0;
    x0 += ks1; x1 += ks2 + 1u;
    x0 += x1; x1 = rotl32(x1, 17); x1 ^= x0;
    x0 += x1; x1 = rotl32(x1, 29); x1 ^= x0;
    x0 += x1; x1 = rotl32(x1, 16); x1 ^= x0;
    x0 += x1; x1 = rotl32(x1, 24); x1 ^= x0;
    x0 += ks2; x1 += ks0 + 2u;
    x0 += x1; x1 = rotl32(x1, 13); x1 ^= x0;
    x0 += x1; x1 = rotl32(x1, 15); x1 ^= x0;
    x0 += x1; x1 = rotl32(x1, 26); x1 ^= x0;
    x0 += x1; x1 = rotl32(x1, 6);  x1 ^= x0;
    x0 += ks0; x1 += ks1 + 3u;
    x0 += x1; x1 = rotl32(x1, 17); x1 ^= x0;
    x0 += x1; x1 = rotl32(x1, 29); x1 ^= x0;
    x0 += x1; x1 = rotl32(x1, 16); x1 ^= x0;
    x0 += x1; x1 = rotl32(x1, 24); x1 ^= x0;
    x0 += ks1; x1 += ks2 + 4u;
    x0 += x1; x1 = rotl32(x1, 13); x1 ^= x0;
    x0 += x1; x1 = rotl32(x1, 15); x1 ^= x0;
    x0 += x1; x1 = rotl32(x1, 26); x1 ^= x0;
    x0 += x1; x1 = rotl32(x1, 6);  x1 ^= x0;
    x0 += ks2; x1 += ks0 + 5u;
    o0 = x0; o1 = x1;
}

// ---------------- Kernels ----------------
// Per-block LDS histogram of coarse buckets, flushed with one global atomic per bucket.
__global__ __launch_bounds__(256) void k_bhist(const int* __restrict__ ei,
                                               int* __restrict__ bhist) {
    __shared__ int h[NBUCK];
    const int tid = threadIdx.x;
    for (int i = tid; i < NBUCK; i += 256) h[i] = 0;
    __syncthreads();
    const int base = blockIdx.x * CHUNK;
    for (int i = tid; i < CHUNK; i += 256) {
        const unsigned t = (unsigned)ei[NE + base + i];
        if (t < NN) atomicAdd(&h[t >> 6], 1);
    }
    __syncthreads();
    for (int i = tid; i < NBUCK; i += 256) {
        const int v = h[i];
        if (v) atomicAdd(&bhist[i], v);
    }
}

// Exclusive scan of bhist (1563 <= 2048) in one block; writes bstart and bcur.
__global__ __launch_bounds__(1024) void k_bscan(const int* __restrict__ bhist,
                                                int* __restrict__ bstart,
                                                int* __restrict__ bcur) {
    __shared__ int s[2048];
    const int t = threadIdx.x;
    const int i0 = t, i1 = t + 1024;
    const int c0 = (i0 < NBUCK) ? bhist[i0] : 0;
    const int c1 = (i1 < NBUCK) ? bhist[i1] : 0;
    s[i0] = c0; s[i1] = c1;
    __syncthreads();
    for (int d = 1; d < 2048; d <<= 1) {
        const int a0 = (i0 >= d) ? s[i0 - d] : 0;
        const int a1 = (i1 >= d) ? s[i1 - d] : 0;
        __syncthreads();
        s[i0] += a0; s[i1] += a1;
        __syncthreads();
    }
    if (i0 < NBUCK) { const int b = s[i0] - c0; bstart[i0] = b; bcur[i0] = b; }
    if (i1 < NBUCK) { const int b = s[i1] - c1; bstart[i1] = b; bcur[i1] = b; }
    if (t == 0) bstart[NBUCK] = NE;
}

// Bin edges: LDS hist -> one cursor atomic per (block,bucket) -> grouped writes.
__global__ __launch_bounds__(256) void k_p1(const int* __restrict__ ei,
                                            int* __restrict__ bcur,
                                            unsigned* __restrict__ packed) {
    __shared__ int hb[NBUCK];   // histogram, then block-local base
    __shared__ int lc[NBUCK];   // local cursor
    const int tid = threadIdx.x;
    for (int i = tid; i < NBUCK; i += 256) { hb[i] = 0; lc[i] = 0; }
    __syncthreads();
    const int base = blockIdx.x * CHUNK;
    for (int i = tid; i < CHUNK; i += 256) {
        const unsigned t = (unsigned)ei[NE + base + i];
        if (t < NN) atomicAdd(&hb[t >> 6], 1);
    }
    __syncthreads();
    for (int i = tid; i < NBUCK; i += 256) {
        const int h = hb[i];
        hb[i] = h ? atomicAdd(&bcur[i], h) : 0;
    }
    __syncthreads();
    for (int i = tid; i < CHUNK; i += 256) {
        const unsigned t = (unsigned)ei[NE + base + i];
        if (t >= NN) continue;
        const unsigned src = (unsigned)ei[base + i];
        const int bk = t >> 6;
        const unsigned pos = (unsigned)(hb[bk] + atomicAdd(&lc[bk], 1));
        if (pos < NE) packed[pos] = src | ((t & 63u) << 17);
    }
}

// Per-bucket degree -> dinv (LDS int counts, coalesced packed reads).
__global__ __launch_bounds__(256) void k_p2a(const unsigned* __restrict__ packed,
                                             const int* __restrict__ bstart,
                                             float* __restrict__ dinv) {
    __shared__ int cnt[64];
    const int tid = threadIdx.x;
    const int b = blockIdx.x;
    if (tid < 64) cnt[tid] = 0;
    __syncthreads();
    int s = bstart[b], e = bstart[b + 1];
    if (s < 0) s = 0;
    if (e > NE) e = NE;
    for (int i = s + tid; i < e; i += 256) atomicAdd(&cnt[packed[i] >> 17], 1);
    __syncthreads();
    if (tid < 64) {
        const int c = b * 64 + tid;
        if (c < NN) dinv[c] = rsqrtf(1.0f + (float)cnt[tid]);
    }
}

// x@W (W staged in LDS), scale by dinv, write xsh (bf16).
__global__ __launch_bounds__(256) void k_xw(const float* __restrict__ x,
                                            const float* __restrict__ W,
                                            const float* __restrict__ dinv,
                                            __hip_bfloat16* __restrict__ xsh) {
    __shared__ float Wl[64 * 64];
    __shared__ float xr[4][64];
    const int tid = threadIdx.x;
    for (int i = tid; i < 64 * 64; i += 256) Wl[i] = W[i];
    const int warp = tid >> 6, lane = tid & 63;
    const int row = blockIdx.x * 4 + warp;  // grid exact: 25000*4 == NN
    xr[warp][lane] = x[(size_t)row * 64 + lane];
    __syncthreads();
    float sum = 0.0f;
#pragma unroll
    for (int k = 0; k < 64; ++k) sum = fmaf(xr[warp][k], Wl[k * 64 + lane], sum);
    xsh[(size_t)row * 64 + lane] = __float2bfloat16(sum * dinv[row]);
}

// Per-bucket aggregation in LDS. 8 waves/block; each wave takes 64 edges at a
// time (per-lane coalesced packed load), then a fully-unrolled 64-step shfl
// broadcast loop of INDEPENDENT gathers + LDS atomics (deep ILP).
__global__ __launch_bounds__(512) void k_p2b(const unsigned* __restrict__ packed,
                                             const int* __restrict__ bstart,
                                             const __hip_bfloat16* __restrict__ xsh,
                                             const float* __restrict__ dinv,
                                             const float* __restrict__ bias,
                                             float* __restrict__ out) {
    __shared__ float acc[64 * 64];  // [tgt_local][dim], 16 KB
    const int tid = threadIdx.x;
    const int b = blockIdx.x;
    const long long pbase = (long long)b * 4096;
    // init with self-loop terms (coalesced)
    for (int idx = tid; idx < 4096; idx += 512) {
        const long long p = pbase + idx;
        acc[idx] = (p < (long long)NN * 64) ? __bfloat162float(xsh[p]) : 0.0f;
    }
    __syncthreads();
    int s = bstart[b], e = bstart[b + 1];
    if (s < 0) s = 0;
    if (e > NE) e = NE;
    const int wid = tid >> 6, lane = tid & 63;
    for (int base = s + wid * 64; base < e; base += 8 * 64) {
        const int idx = base + lane;
        const unsigned pk = (idx < e) ? packed[idx] : 0u;  // coalesced, 64 edges/wave
        if (base + 64 <= e) {
#pragma unroll
            for (int j = 0; j < 64; ++j) {
                const unsigned pj = __shfl(pk, j);
                const int src = (int)(pj & 0x1FFFFu);
                const int tl  = (int)(pj >> 17);
                const float v = __bfloat162float(xsh[(size_t)src * 64 + lane]);
                atomicAdd(&acc[(tl << 6) + lane], v);
            }
        } else {
            const int m = e - base;
            for (int j = 0; j < m; ++j) {
                const unsigned pj = __shfl(pk, j);
                const int src = (int)(pj & 0x1FFFFu);
                const int tl  = (int)(pj >> 17);
                const float v = __bfloat162float(xsh[(size_t)src * 64 + lane]);
                atomicAdd(&acc[(tl << 6) + lane], v);
            }
        }
    }
    __syncthreads();
    // finalize: bias + tanh + JAX dropout, coalesced out writes
    for (int idx = tid; idx < 4096; idx += 512) {
        const long long p = pbase + idx;
        if (p >= (long long)NN * 64) break;
        const int c = (int)(p >> 6);
        unsigned o0, o1;
        threefry2x32(0u, 42u, 0u, (unsigned)p, o0, o1);
        const unsigned bits = o0 ^ o1;
        const float u = __uint_as_float((bits >> 9) | 0x3f800000u) - 1.0f;
        const float h = tanhf(dinv[c] * acc[idx] + bias[idx & 63]);
        out[p] = (u < 0.9f) ? h / 0.9f : 0.0f;
    }
}

extern "C" void kernel_launch(void* const* d_in, const int* in_sizes, int n_in,
                              void* d_out, int out_size, void* d_ws, size_t ws_size,
                              hipStream_t stream) {
    const float* x  = (const float*)d_in[0];
    const float* W  = (const float*)d_in[1];
    const float* b  = (const float*)d_in[2];
    const int*   ei = (const int*)d_in[3];
    float* out = (float*)d_out;

    float* dinv = (float*)d_ws;                          // f32[NN]
    __hip_bfloat16* xsh = (__hip_bfloat16*)(dinv + NN);  // bf16[NN*64]
    unsigned* packed = (unsigned*)(xsh + (size_t)NN * 64);  // u32[NE]
    int* bhist  = (int*)(packed + NE);                   // i32[NBUCK]
    int* bstart = bhist + NBUCK;                         // i32[NBUCK+1]
    int* bcur   = bstart + NBUCK + 1;                    // i32[NBUCK]

    hipMemsetAsync(bhist, 0, NBUCK * sizeof(int), stream);
    k_bhist<<<P1B, 256, 0, stream>>>(ei, bhist);
    k_bscan<<<1, 1024, 0, stream>>>(bhist, bstart, bcur);
    k_p1<<<P1B, 256, 0, stream>>>(ei, bcur, packed);
    k_p2a<<<NBUCK, 256, 0, stream>>>(packed, bstart, dinv);
    k_xw<<<NN / 4, 256, 0, stream>>>(x, W, dinv, xsh);
    k_p2b<<<NBUCK, 512, 0, stream>>>(packed, bstart, xsh, dinv, b, out);
}

// Round 9
// 198.810 us; speedup vs baseline: 3.8101x; 3.7859x over previous
//
#include <hip/hip_runtime.h>
#include <hip/hip_bf16.h>

// GCNConv: coarse bin (64 tgts/bucket, grouped writes) -> per-bucket LDS
// counting sort to per-node CSR (in place over packed) -> per-node wave gather.
// agg[c] = dinv[c] * ( xs[c] + sum_{e: col[e]==c} xs[row[e]] ),
//   xs[i] = (x@W)[i] * dinv[i],  dinv[i] = rsqrt(1 + indeg(i))
// out = dropout(tanh(agg + b)), JAX partitionable-threefry key (0,42), p_keep=0.9:
//   bits[p] = o0^o1 of threefry((0,42), 0, p); u = bitcast(bits>>9|0x3f800000)-1; keep = u<0.9.
//
// NOTE (R8 lesson): __shfl sources must be lanes that are ACTIVE — keep all
// broadcast loops uniform across the wave (ds_bpermute from EXEC-off lanes is
// undefined). ILP comes from manual 4-way unroll with uniform j, not lane-splits.
//
// ws (20.0 MB): dinv f32[NN] | xsh bf16[NN*64] | packed u32[NE] |
//               noff u32[NN] | bhist i32[NBUCK] | bstart i32[NBUCK+1] | bcur i32[NBUCK]
// packed (phase 1): src(17b) | tgt_local(6b)<<17, bucket = tgt>>6.
// packed (after sortb, per bucket): plain src, grouped by node.
// noff[c] = off(21b) | min(deg,2047)<<21 ; deg-field 2047 => scan-mode fallback.

#define NN 100000
#define NE 1600000
#define NBUCK 1563
#define P1B 128
#define CHUNK 12500         // P1B * CHUNK == NE
#define STAGE_CAP 2560      // > mean(1024) + 48 sigma; fallback if exceeded

// ---------------- Threefry2x32 (JAX-exact) ----------------
__device__ __forceinline__ unsigned rotl32(unsigned x, int r) {
    return (x << r) | (x >> (32 - r));
}

__device__ __forceinline__ void threefry2x32(unsigned k0, unsigned k1,
                                             unsigned x0, unsigned x1,
                                             unsigned& o0, unsigned& o1) {
    const unsigned ks0 = k0, ks1 = k1, ks2 = k0 ^ k1 ^ 0x1BD11BDAu;
    x0 += ks0; x1 += ks1;
    x0 += x1; x1 = rotl32(x1, 13); x1 ^= x0;
    x0 += x1; x1 = rotl32(x1, 15); x1 ^= x0;
    x0 += x1; x1 = rotl32(x1, 26); x1 ^= x0;
    x0 += x1; x1 = rotl32(x1, 6);  x1 ^= x0;
    x0 += ks1; x1 += ks2 + 1u;
    x0 += x1; x1 = rotl32(x1, 17); x1 ^= x0;
    x0 += x1; x1 = rotl32(x1, 29); x1 ^= x0;
    x0 += x1; x1 = rotl32(x1, 16); x1 ^= x0;
    x0 += x1; x1 = rotl32(x1, 24); x1 ^= x0;
    x0 += ks2; x1 += ks0 + 2u;
    x0 += x1; x1 = rotl32(x1, 13); x1 ^= x0;
    x0 += x1; x1 = rotl32(x1, 15); x1 ^= x0;
    x0 += x1; x1 = rotl32(x1, 26); x1 ^= x0;
    x0 += x1; x1 = rotl32(x1, 6);  x1 ^= x0;
    x0 += ks0; x1 += ks1 + 3u;
    x0 += x1; x1 = rotl32(x1, 17); x1 ^= x0;
    x0 += x1; x1 = rotl32(x1, 29); x1 ^= x0;
    x0 += x1; x1 = rotl32(x1, 16); x1 ^= x0;
    x0 += x1; x1 = rotl32(x1, 24); x1 ^= x0;
    x0 += ks1; x1 += ks2 + 4u;
    x0 += x1; x1 = rotl32(x1, 13); x1 ^= x0;
    x0 += x1; x1 = rotl32(x1, 15); x1 ^= x0;
    x0 += x1; x1 = rotl32(x1, 26); x1 ^= x0;
    x0 += x1; x1 = rotl32(x1, 6);  x1 ^= x0;
    x0 += ks2; x1 += ks0 + 5u;
    o0 = x0; o1 = x1;
}

// ---------------- Kernels ----------------
__global__ __launch_bounds__(256) void k_bhist(const int* __restrict__ ei,
                                               int* __restrict__ bhist) {
    __shared__ int h[NBUCK];
    const int tid = threadIdx.x;
    for (int i = tid; i < NBUCK; i += 256) h[i] = 0;
    __syncthreads();
    const int base = blockIdx.x * CHUNK;
    for (int i = tid; i < CHUNK; i += 256) {
        const unsigned t = (unsigned)ei[NE + base + i];
        if (t < NN) atomicAdd(&h[t >> 6], 1);
    }
    __syncthreads();
    for (int i = tid; i < NBUCK; i += 256) {
        const int v = h[i];
        if (v) atomicAdd(&bhist[i], v);
    }
}

__global__ __launch_bounds__(1024) void k_bscan(const int* __restrict__ bhist,
                                                int* __restrict__ bstart,
                                                int* __restrict__ bcur) {
    __shared__ int s[2048];
    const int t = threadIdx.x;
    const int i0 = t, i1 = t + 1024;
    const int c0 = (i0 < NBUCK) ? bhist[i0] : 0;
    const int c1 = (i1 < NBUCK) ? bhist[i1] : 0;
    s[i0] = c0; s[i1] = c1;
    __syncthreads();
    for (int d = 1; d < 2048; d <<= 1) {
        const int a0 = (i0 >= d) ? s[i0 - d] : 0;
        const int a1 = (i1 >= d) ? s[i1 - d] : 0;
        __syncthreads();
        s[i0] += a0; s[i1] += a1;
        __syncthreads();
    }
    if (i0 < NBUCK) { const int b = s[i0] - c0; bstart[i0] = b; bcur[i0] = b; }
    if (i1 < NBUCK) { const int b = s[i1] - c1; bstart[i1] = b; bcur[i1] = b; }
    if (t == 0) bstart[NBUCK] = NE;
}

__global__ __launch_bounds__(256) void k_p1(const int* __restrict__ ei,
                                            int* __restrict__ bcur,
                                            unsigned* __restrict__ packed) {
    __shared__ int hb[NBUCK];
    __shared__ int lc[NBUCK];
    const int tid = threadIdx.x;
    for (int i = tid; i < NBUCK; i += 256) { hb[i] = 0; lc[i] = 0; }
    __syncthreads();
    const int base = blockIdx.x * CHUNK;
    for (int i = tid; i < CHUNK; i += 256) {
        const unsigned t = (unsigned)ei[NE + base + i];
        if (t < NN) atomicAdd(&hb[t >> 6], 1);
    }
    __syncthreads();
    for (int i = tid; i < NBUCK; i += 256) {
        const int h = hb[i];
        hb[i] = h ? atomicAdd(&bcur[i], h) : 0;
    }
    __syncthreads();
    for (int i = tid; i < CHUNK; i += 256) {
        const unsigned t = (unsigned)ei[NE + base + i];
        if (t >= NN) continue;
        const unsigned src = (unsigned)ei[base + i];
        const int bk = t >> 6;
        const unsigned pos = (unsigned)(hb[bk] + atomicAdd(&lc[bk], 1));
        if (pos < NE) packed[pos] = src | ((t & 63u) << 17);
    }
}

// Per-bucket: tl-histogram -> dinv + noff; LDS-stage + counting-sort the
// segment back over packed (node-grouped, tl stripped). Fallback: scan-mode.
__global__ __launch_bounds__(256) void k_sortb(unsigned* __restrict__ packed,
                                               const int* __restrict__ bstart,
                                               float* __restrict__ dinv,
                                               unsigned* __restrict__ noff) {
    __shared__ unsigned stage[STAGE_CAP];
    __shared__ int hist[64];
    __shared__ int pref[64];
    __shared__ int cur[64];
    const int tid = threadIdx.x;
    const int b = blockIdx.x;
    int s = bstart[b], e = bstart[b + 1];
    if (s < 0) s = 0;
    if (e > NE) e = NE;
    if (e < s) e = s;
    const int seg = e - s;
    if (tid < 64) hist[tid] = 0;
    __syncthreads();
    for (int i = s + tid; i < e; i += 256) atomicAdd(&hist[packed[i] >> 17], 1);
    __syncthreads();
    if (tid == 0) {
        int run = 0;
        for (int t = 0; t < 64; ++t) { pref[t] = run; run += hist[t]; }
    }
    __syncthreads();
    if (tid < 64) cur[tid] = pref[tid];
    const bool oversize = (seg > STAGE_CAP);
    if (tid < 64) {
        const int c = b * 64 + tid;
        if (c < NN) {
            const int deg = hist[tid];
            dinv[c] = rsqrtf(1.0f + (float)deg);
            const unsigned dcap = oversize ? 2047u
                                           : ((deg > 2046) ? 2047u : (unsigned)deg);
            noff[c] = (unsigned)(s + pref[tid]) | (dcap << 21);
        }
    }
    if (oversize) return;  // segment left in src|tl form; k_agg scans it
    __syncthreads();
    for (int i = s + tid; i < e; i += 256) stage[i - s] = packed[i];
    __syncthreads();
    for (int k = tid; k < seg; k += 256) {
        const unsigned pk = stage[k];
        const int tl = (int)(pk >> 17);
        const int pos = s + atomicAdd(&cur[tl], 1);
        packed[pos] = pk & 0x1FFFFu;
    }
}

// x@W (W staged in LDS), scale by dinv, write xsh (bf16).
__global__ __launch_bounds__(256) void k_xw(const float* __restrict__ x,
                                            const float* __restrict__ W,
                                            const float* __restrict__ dinv,
                                            __hip_bfloat16* __restrict__ xsh) {
    __shared__ float Wl[64 * 64];
    __shared__ float xr[4][64];
    const int tid = threadIdx.x;
    for (int i = tid; i < 64 * 64; i += 256) Wl[i] = W[i];
    const int warp = tid >> 6, lane = tid & 63;
    const int row = blockIdx.x * 4 + warp;  // grid exact: 25000*4 == NN
    xr[warp][lane] = x[(size_t)row * 64 + lane];
    __syncthreads();
    float sum = 0.0f;
#pragma unroll
    for (int k = 0; k < 64; ++k) sum = fmaf(xr[warp][k], Wl[k * 64 + lane], sum);
    xsh[(size_t)row * 64 + lane] = __float2bfloat16(sum * dinv[row]);
}

// One wave per node, lane = dim. Uniform __shfl broadcast loop, manually
// unrolled x4 into 4 independent accumulator chains (ILP), uniform tail.
// Fused bias + tanh + JAX dropout epilogue; coalesced out writes.
__global__ __launch_bounds__(256) void k_agg(const unsigned* __restrict__ packed,
                                             const unsigned* __restrict__ noff,
                                             const int* __restrict__ bstart,
                                             const __hip_bfloat16* __restrict__ xsh,
                                             const float* __restrict__ dinv,
                                             const float* __restrict__ bias,
                                             float* __restrict__ out) {
    const int tid = threadIdx.x;
    const int c = blockIdx.x * 4 + (tid >> 6);  // grid exact: 25000*4 == NN
    const int lane = tid & 63;
    const unsigned info = noff[c];
    const int off = (int)(info & 0x1FFFFFu);
    const int dcap = (int)(info >> 21);

    float a0 = __bfloat162float(xsh[(size_t)c * 64 + lane]);  // self-loop term
    float a1 = 0.0f, a2 = 0.0f, a3 = 0.0f;
    if (dcap < 2047) {
        for (int base = 0; base < dcap; base += 64) {
            const int m = (dcap - base < 64) ? (dcap - base) : 64;
            const unsigned sv = (lane < m) ? packed[off + base + lane] : 0u;
            int j = 0;
            for (; j + 3 < m; j += 4) {  // uniform trip count, all lanes active
                const int s0 = (int)__shfl(sv, j);
                const int s1 = (int)__shfl(sv, j + 1);
                const int s2 = (int)__shfl(sv, j + 2);
                const int s3 = (int)__shfl(sv, j + 3);
                a0 += __bfloat162float(xsh[(size_t)s0 * 64 + lane]);
                a1 += __bfloat162float(xsh[(size_t)s1 * 64 + lane]);
                a2 += __bfloat162float(xsh[(size_t)s2 * 64 + lane]);
                a3 += __bfloat162float(xsh[(size_t)s3 * 64 + lane]);
            }
            for (; j < m; ++j) {  // uniform tail
                const int s0 = (int)__shfl(sv, j);
                a0 += __bfloat162float(xsh[(size_t)s0 * 64 + lane]);
            }
        }
    } else {  // scan-mode fallback (oversized bucket; segment still src|tl)
        const int b = c >> 6;
        int ss = bstart[b], ee = bstart[b + 1];
        if (ss < 0) ss = 0;
        if (ee > NE) ee = NE;
        const unsigned tl = (unsigned)(c & 63);
        for (int i = ss; i < ee; ++i) {
            const unsigned pk = packed[i];  // uniform address: broadcast load
            if ((pk >> 17) == tl)
                a0 += __bfloat162float(xsh[(size_t)(pk & 0x1FFFFu) * 64 + lane]);
        }
    }
    const float a = (a0 + a1) + (a2 + a3);
    const int p = c * 64 + lane;
    unsigned o0, o1;
    threefry2x32(0u, 42u, 0u, (unsigned)p, o0, o1);
    const unsigned bits = o0 ^ o1;
    const float u = __uint_as_float((bits >> 9) | 0x3f800000u) - 1.0f;
    const float h = tanhf(dinv[c] * a + bias[lane]);
    out[p] = (u < 0.9f) ? h / 0.9f : 0.0f;
}

extern "C" void kernel_launch(void* const* d_in, const int* in_sizes, int n_in,
                              void* d_out, int out_size, void* d_ws, size_t ws_size,
                              hipStream_t stream) {
    const float* x  = (const float*)d_in[0];
    const float* W  = (const float*)d_in[1];
    const float* b  = (const float*)d_in[2];
    const int*   ei = (const int*)d_in[3];
    float* out = (float*)d_out;

    float* dinv = (float*)d_ws;                             // f32[NN]
    __hip_bfloat16* xsh = (__hip_bfloat16*)(dinv + NN);     // bf16[NN*64]
    unsigned* packed = (unsigned*)(xsh + (size_t)NN * 64);  // u32[NE]
    unsigned* noff = packed + NE;                           // u32[NN]
    int* bhist  = (int*)(noff + NN);                        // i32[NBUCK]
    int* bstart = bhist + NBUCK;                            // i32[NBUCK+1]
    int* bcur   = bstart + NBUCK + 1;                       // i32[NBUCK]

    hipMemsetAsync(bhist, 0, NBUCK * sizeof(int), stream);
    k_bhist<<<P1B, 256, 0, stream>>>(ei, bhist);
    k_bscan<<<1, 1024, 0, stream>>>(bhist, bstart, bcur);
    k_p1<<<P1B, 256, 0, stream>>>(ei, bcur, packed);
    k_sortb<<<NBUCK, 256, 0, stream>>>(packed, bstart, dinv, noff);
    k_xw<<<NN / 4, 256, 0, stream>>>(x, W, dinv, xsh);
    k_agg<<<NN / 4, 256, 0, stream>>>(packed, noff, bstart, xsh, dinv, b, out);
}